// Round 1
// baseline (323.711 us; speedup 1.0000x reference)
//
#include <hip/hip_runtime.h>
#include <math.h>

#define B_ROWS 65536
#define N_COLS 512
#define EPS 1e-8f

// ws layout (floats):
//   [0, B_ROWS)             sim
//   [B_ROWS, B_ROWS+512)    colsum (anchors_prob column sums)
//   [B_ROWS+512, +4)        acc[0]=sum max(log sim,-100)
//                           acc[1]=sum max(sim,eps)*max(log sim,eps)
//                           acc[2]=sum max(toe,eps)*max(log toe,eps)

__device__ __forceinline__ float wave_reduce_sum(float v) {
#pragma unroll
    for (int m = 32; m >= 1; m >>= 1) v += __shfl_xor(v, m, 64);
    return v;
}
__device__ __forceinline__ float wave_reduce_max(float v) {
#pragma unroll
    for (int m = 32; m >= 1; m >>= 1) v = fmaxf(v, __shfl_xor(v, m, 64));
    return v;
}

__global__ __launch_bounds__(256) void scan_pass1(
        const float* __restrict__ A, const float* __restrict__ Bn,
        float* __restrict__ sim, float* __restrict__ colsum,
        float* __restrict__ acc) {
    __shared__ float cs[512];
    __shared__ float slog[4];
    __shared__ float ssec[4];

    const int t    = threadIdx.x;
    const int lane = t & 63;
    const int wv   = t >> 6;
    const int wave = (blockIdx.x * blockDim.x + t) >> 6;
    const int nwaves = (gridDim.x * blockDim.x) >> 6;

    float cacc[8];
#pragma unroll
    for (int k = 0; k < 8; ++k) cacc[k] = 0.f;
    float accLog = 0.f, accSec = 0.f;

    for (int i = wave; i < B_ROWS; i += nwaves) {
        const float* a = A  + (size_t)i * N_COLS;
        const float* b = Bn + (size_t)i * N_COLS;
        float4 a0 = *(const float4*)(a + lane * 4);
        float4 a1 = *(const float4*)(a + 256 + lane * 4);
        float4 b0 = *(const float4*)(b + lane * 4);
        float4 b1 = *(const float4*)(b + 256 + lane * 4);
        float av[8] = {a0.x, a0.y, a0.z, a0.w, a1.x, a1.y, a1.z, a1.w};
        float bv[8] = {b0.x, b0.y, b0.z, b0.w, b1.x, b1.y, b1.z, b1.w};

        float ma = av[0], mb = bv[0];
#pragma unroll
        for (int k = 1; k < 8; ++k) { ma = fmaxf(ma, av[k]); mb = fmaxf(mb, bv[k]); }
        ma = wave_reduce_max(ma);
        mb = wave_reduce_max(mb);

        float ea[8];
        float sa = 0.f, sb = 0.f, dp = 0.f;
#pragma unroll
        for (int k = 0; k < 8; ++k) {
            ea[k]    = __expf(av[k] - ma);
            float eb = __expf(bv[k] - mb);
            sa += ea[k];
            sb += eb;
            dp += ea[k] * eb;
        }
        sa = wave_reduce_sum(sa);
        sb = wave_reduce_sum(sb);
        dp = wave_reduce_sum(dp);

        float inv_sa = 1.f / sa;
        float s = dp * inv_sa * (1.f / sb);
#pragma unroll
        for (int k = 0; k < 8; ++k) cacc[k] += ea[k] * inv_sa;

        if (lane == 0) {
            sim[i] = s;
            float lg = __logf(s);
            accLog += fmaxf(lg, -100.f);
            accSec += fmaxf(s, EPS) * fmaxf(lg, EPS);
        }
    }

    // block-level column reduction: LDS, then one global atomic per column
    cs[t] = 0.f; cs[t + 256] = 0.f;
    __syncthreads();
#pragma unroll
    for (int k = 0; k < 4; ++k) atomicAdd(&cs[lane * 4 + k], cacc[k]);
#pragma unroll
    for (int k = 0; k < 4; ++k) atomicAdd(&cs[256 + lane * 4 + k], cacc[4 + k]);
    if (lane == 0) { slog[wv] = accLog; ssec[wv] = accSec; }
    __syncthreads();
    atomicAdd(&colsum[t], cs[t]);
    atomicAdd(&colsum[t + 256], cs[t + 256]);
    if (t == 0) {
        atomicAdd(&acc[0], slog[0] + slog[1] + slog[2] + slog[3]);
        atomicAdd(&acc[1], ssec[0] + ssec[1] + ssec[2] + ssec[3]);
    }
}

__global__ __launch_bounds__(256) void scan_pass2(
        const float* __restrict__ A, const float* __restrict__ sim,
        float* __restrict__ acc) {
    __shared__ float sthird[4];
    const int t    = threadIdx.x;
    const int lane = t & 63;
    const int wv   = t >> 6;
    const int wave = (blockIdx.x * blockDim.x + t) >> 6;
    const int nwaves = (gridDim.x * blockDim.x) >> 6;

    float accThird = 0.f;
    for (int i = wave; i < B_ROWS; i += nwaves) {
        const float* a = A + (size_t)i * N_COLS;
        // tile(sim, n).reshape(b,n): row i uses sim[(i*512+j) % 65536]
        //  = contiguous slab starting at (i & 127) * 512  (stride nwaves keeps
        //    i&127 fixed per wave -> slab stays L1-resident)
        const float* s = sim + (size_t)(i & 127) * N_COLS;
        float4 a0 = *(const float4*)(a + lane * 4);
        float4 a1 = *(const float4*)(a + 256 + lane * 4);
        float4 s0 = *(const float4*)(s + lane * 4);
        float4 s1 = *(const float4*)(s + 256 + lane * 4);
        float av[8] = {a0.x, a0.y, a0.z, a0.w, a1.x, a1.y, a1.z, a1.w};
        float sv[8] = {s0.x, s0.y, s0.z, s0.w, s1.x, s1.y, s1.z, s1.w};

        float ma = av[0];
#pragma unroll
        for (int k = 1; k < 8; ++k) ma = fmaxf(ma, av[k]);
        ma = wave_reduce_max(ma);

        float sa = 0.f, dp = 0.f;
#pragma unroll
        for (int k = 0; k < 8; ++k) {
            float e = __expf(av[k] - ma);
            sa += e;
            dp += e * sv[k];
        }
        sa = wave_reduce_sum(sa);
        dp = wave_reduce_sum(dp);

        if (lane == 0) {
            float toe = dp / sa;
            float lg  = __logf(toe);
            accThird += fmaxf(toe, EPS) * fmaxf(lg, EPS);
        }
    }
    if (lane == 0) sthird[wv] = accThird;
    __syncthreads();
    if (t == 0)
        atomicAdd(&acc[2], sthird[0] + sthird[1] + sthird[2] + sthird[3]);
}

__global__ __launch_bounds__(64) void scan_finalize(
        const float* __restrict__ colsum, const float* __restrict__ acc,
        float* __restrict__ out) {
    const int lane = threadIdx.x;
    float e = 0.f;
#pragma unroll
    for (int k = 0; k < 8; ++k) {
        float p = colsum[lane * 8 + k] * (1.f / B_ROWS);
        p = fmaxf(p, EPS);
        e -= p * __logf(p);
    }
    e = wave_reduce_sum(e);
    if (lane == 0) {
        float consistency = -acc[0] * (1.f / B_ROWS);
        float second      = acc[1];
        float third       = acc[2] * (1.f / N_COLS);
        float entropy     = e;
        float third_weight = 0.5f / sqrtf((float)N_COLS);
        float diff_weight  = 0.25f / (float)N_COLS;
        float total = consistency - 2.0f * entropy + diff_weight * second
                      - third_weight * third;
        out[0] = total;
        out[1] = consistency;
        out[2] = entropy;
        out[3] = second;
        out[4] = third;
    }
}

extern "C" void kernel_launch(void* const* d_in, const int* in_sizes, int n_in,
                              void* d_out, int out_size, void* d_ws, size_t ws_size,
                              hipStream_t stream) {
    const float* anchors   = (const float*)d_in[0];
    const float* neighbors = (const float*)d_in[1];
    float* out = (float*)d_out;

    float* sim    = (float*)d_ws;              // 65536 floats
    float* colsum = sim + B_ROWS;              // 512 floats
    float* acc    = colsum + N_COLS;           // 4 floats

    // zero the accumulators (ws is re-poisoned before every call)
    hipMemsetAsync(colsum, 0, (N_COLS + 4) * sizeof(float), stream);

    dim3 block(256);
    dim3 grid(1024);   // 4096 waves, 16 rows each; 16 waves/CU
    scan_pass1<<<grid, block, 0, stream>>>(anchors, neighbors, sim, colsum, acc);
    scan_pass2<<<grid, block, 0, stream>>>(anchors, sim, acc);
    scan_finalize<<<1, 64, 0, stream>>>(colsum, acc, out);
}